// Round 1
// baseline (1076.739 us; speedup 1.0000x reference)
//
#include <hip/hip_runtime.h>
#include <hip/hip_bf16.h>

#define D_DIM 256
#define EPS_BN 1e-6f
#define EPS_SM 1e-8f
#define BK 16
#define LDP 68   // padded LDS leading dim: 16B-aligned rows (68*4=272), banks spread

__device__ __forceinline__ float wave_reduce_sum(float v) {
    #pragma unroll
    for (int off = 1; off < 64; off <<= 1) v += __shfl_xor(v, off);
    return v;
}

__device__ __forceinline__ float sigmoidf_(float x) {
    return 1.0f / (1.0f + __expf(-x));
}

// ---------------------------------------------------------------------------
// K1: one block (256 thr = 4 waves) per molecule. mol_index is sorted, so the
// molecule's atoms are a contiguous range found by binary search.
// Computes: align scores (leaky-relu), segment softmax, attention weights,
// normalized weighted atom sum ctxwn[m,:] = sum_i w_i * atom_i, and
// wsum[m] = (sum_i w_i) = S/(S+eps).
// att_out (the [N] attention-weight output) is used as score/exp scratch and
// finally holds the weights. Each block touches only its own segment.
// ---------------------------------------------------------------------------
__global__ __launch_bounds__(256) void k1_segment(
    const float* __restrict__ superatom,
    const float* __restrict__ atom,
    const int*   __restrict__ mol_index,
    const float* __restrict__ align_w,
    const float* __restrict__ align_b,
    float* __restrict__ ctxwn,   // [M, D]
    float* __restrict__ wsum,    // [M]
    float* __restrict__ att_out, // [N]
    int N)
{
    const int m    = blockIdx.x;
    const int tid  = threadIdx.x;
    const int wid  = tid >> 6;
    const int lane = tid & 63;

    // binary search segment [segs, sege)
    int lo = 0, hi = N;
    while (lo < hi) { int mid = (lo + hi) >> 1; if (mol_index[mid] < m) lo = mid + 1; else hi = mid; }
    const int segs = lo;
    hi = N;
    while (lo < hi) { int mid = (lo + hi) >> 1; if (mol_index[mid] < m + 1) lo = mid + 1; else hi = mid; }
    const int sege = lo;

    // c_m = dot(align_w[0:D], superatom[m]) + b   (redundant per wave, cheap)
    const float4* sup4 = (const float4*)(superatom + (size_t)m * D_DIM);
    const float4* w14  = (const float4*)align_w;
    const float4* w24  = (const float4*)(align_w + D_DIM);
    float4 sw = sup4[lane];
    float4 w1 = w14[lane];
    float part = sw.x * w1.x + sw.y * w1.y + sw.z * w1.z + sw.w * w1.w;
    part = wave_reduce_sum(part);
    const float cm = part + align_b[0];
    const float4 wa = w24[lane];

    __shared__ float smax[4];
    __shared__ float ssum[4];
    __shared__ float sacc[4 * D_DIM];

    // ---- phase A: scores + segment max (one atom per wave) ----
    float lmax = -3.4e38f;
    for (int i = segs + wid; i < sege; i += 4) {
        float4 a = ((const float4*)(atom + (size_t)i * D_DIM))[lane];
        float p = a.x * wa.x + a.y * wa.y + a.z * wa.z + a.w * wa.w;
        p = wave_reduce_sum(p);
        float sc = cm + p;
        sc = sc > 0.0f ? sc : 0.01f * sc;      // leaky_relu(0.01)
        if (lane == 0) att_out[i] = sc;
        lmax = fmaxf(lmax, sc);
    }
    if (lane == 0) smax[wid] = lmax;
    __syncthreads();
    const float bmax = fmaxf(fmaxf(smax[0], smax[1]), fmaxf(smax[2], smax[3]));

    // ---- phase B: e = exp(s-max), S, weighted atom sum (atom rows L2-hot) ----
    float4 acc = make_float4(0.f, 0.f, 0.f, 0.f);
    float S = 0.0f;
    for (int i = segs + wid; i < sege; i += 4) {
        float sc = att_out[i];                  // same wave wrote it
        float e = __expf(sc - bmax);
        S += e;
        float4 a = ((const float4*)(atom + (size_t)i * D_DIM))[lane];
        acc.x += e * a.x; acc.y += e * a.y; acc.z += e * a.z; acc.w += e * a.w;
        if (lane == 0) att_out[i] = e;
    }
    ((float4*)sacc)[wid * 64 + lane] = acc;
    if (lane == 0) ssum[wid] = S;
    __syncthreads();

    const float Stot = ssum[0] + ssum[1] + ssum[2] + ssum[3];
    const float inv  = 1.0f / (Stot + EPS_SM);
    float v = sacc[tid] + sacc[D_DIM + tid] + sacc[2 * D_DIM + tid] + sacc[3 * D_DIM + tid];
    ctxwn[(size_t)m * D_DIM + tid] = v * inv;
    if (tid == 0) wsum[m] = Stot * inv;

    // ---- phase C: final weights ----
    for (int i = segs + tid; i < sege; i += 256) {
        att_out[i] = att_out[i] * inv;
    }
}

// ---------------------------------------------------------------------------
// K2: context = elu( (ctxwn @ attend_w^T) * scale + wsum ⊗ cbias )
//   scale_d = gamma_d * rsqrt(var_d + eps)
//   cbias_d = (attend_b_d - mean_d) * scale_d + beta_d
// 64x64 tile, 256 threads, 4x4 per thread, K staged in LDS k-major.
// ---------------------------------------------------------------------------
__global__ __launch_bounds__(256) void k2_context(
    const float* __restrict__ A,   // ctxwn [M, 256]
    const float* __restrict__ W,   // attend_w [256, 256] (row = out)
    const float* __restrict__ attend_b,
    const float* __restrict__ gamma_, const float* __restrict__ beta_,
    const float* __restrict__ mean_,  const float* __restrict__ var_,
    const float* __restrict__ wsum,
    float* __restrict__ context)
{
    __shared__ float As[BK][LDP];
    __shared__ float Bs[BK][LDP];
    const int m0  = blockIdx.x * 64;
    const int n0  = blockIdx.y * 64;
    const int tid = threadIdx.x;
    const int tx  = tid & 15;     // n
    const int ty  = tid >> 4;     // m

    float acc[4][4] = {};

    for (int kk = 0; kk < D_DIM; kk += BK) {
        #pragma unroll
        for (int it = 0; it < 4; ++it) {
            int r = (tid >> 4) + it * 16;
            int c = tid & 15;
            As[c][r] = A[(size_t)(m0 + r) * D_DIM + kk + c];
            Bs[c][r] = W[(size_t)(n0 + r) * D_DIM + kk + c];
        }
        __syncthreads();
        #pragma unroll
        for (int k = 0; k < BK; ++k) {
            float4 a4 = *(const float4*)&As[k][ty * 4];
            float4 b4 = *(const float4*)&Bs[k][tx * 4];
            float av[4] = {a4.x, a4.y, a4.z, a4.w};
            float bv[4] = {b4.x, b4.y, b4.z, b4.w};
            #pragma unroll
            for (int i = 0; i < 4; ++i)
                #pragma unroll
                for (int j = 0; j < 4; ++j)
                    acc[i][j] = fmaf(av[i], bv[j], acc[i][j]);
        }
        __syncthreads();
    }

    #pragma unroll
    for (int j = 0; j < 4; ++j) {
        int d = n0 + tx * 4 + j;
        float sc = gamma_[d] * rsqrtf(var_[d] + EPS_BN);
        float cb = (attend_b[d] - mean_[d]) * sc + beta_[d];
        #pragma unroll
        for (int i = 0; i < 4; ++i) {
            int row = m0 + ty * 4 + i;
            float pre = acc[i][j] * sc + wsum[row] * cb;
            context[(size_t)row * D_DIM + d] = pre > 0.0f ? pre : (__expf(pre) - 1.0f);
        }
    }
}

// ---------------------------------------------------------------------------
// K3: fused GRU. One block computes a 64(row) x 64(d) tile of the final
// update, accumulating all six sub-GEMMs (context x wih_{r,z,n},
// superatom x whh_{r,z,n}) in registers; gates fused in the epilogue.
// ---------------------------------------------------------------------------
__global__ __launch_bounds__(256) void k3_gru(
    const float* __restrict__ context,   // [M, 256]
    const float* __restrict__ superatom, // [M, 256]
    const float* __restrict__ wih,       // [768, 256]
    const float* __restrict__ whh,       // [768, 256]
    const float* __restrict__ bih,       // [768]
    const float* __restrict__ bhh,       // [768]
    float* __restrict__ out)             // [M, 256]
{
    __shared__ float Ac[BK][LDP];
    __shared__ float Ah[BK][LDP];
    __shared__ float Bs[6][BK][LDP];
    const int m0  = blockIdx.x * 64;
    const int n0  = blockIdx.y * 64;
    const int tid = threadIdx.x;
    const int tx  = tid & 15;
    const int ty  = tid >> 4;

    float acc[6][4][4] = {};

    for (int kk = 0; kk < D_DIM; kk += BK) {
        #pragma unroll
        for (int it = 0; it < 4; ++it) {
            int r = (tid >> 4) + it * 16;
            int c = tid & 15;
            Ac[c][r] = context[(size_t)(m0 + r) * D_DIM + kk + c];
            Ah[c][r] = superatom[(size_t)(m0 + r) * D_DIM + kk + c];
            #pragma unroll
            for (int g = 0; g < 3; ++g) {
                Bs[g][c][r]     = wih[(size_t)(g * D_DIM + n0 + r) * D_DIM + kk + c];
                Bs[3 + g][c][r] = whh[(size_t)(g * D_DIM + n0 + r) * D_DIM + kk + c];
            }
        }
        __syncthreads();
        #pragma unroll
        for (int k = 0; k < BK; ++k) {
            float4 c4 = *(const float4*)&Ac[k][ty * 4];
            float4 h4 = *(const float4*)&Ah[k][ty * 4];
            float cv[4] = {c4.x, c4.y, c4.z, c4.w};
            float hv[4] = {h4.x, h4.y, h4.z, h4.w};
            float bv[6][4];
            #pragma unroll
            for (int g = 0; g < 6; ++g) {
                float4 b4 = *(const float4*)&Bs[g][k][tx * 4];
                bv[g][0] = b4.x; bv[g][1] = b4.y; bv[g][2] = b4.z; bv[g][3] = b4.w;
            }
            #pragma unroll
            for (int i = 0; i < 4; ++i)
                #pragma unroll
                for (int j = 0; j < 4; ++j) {
                    acc[0][i][j] = fmaf(cv[i], bv[0][j], acc[0][i][j]);
                    acc[1][i][j] = fmaf(cv[i], bv[1][j], acc[1][i][j]);
                    acc[2][i][j] = fmaf(cv[i], bv[2][j], acc[2][i][j]);
                    acc[3][i][j] = fmaf(hv[i], bv[3][j], acc[3][i][j]);
                    acc[4][i][j] = fmaf(hv[i], bv[4][j], acc[4][i][j]);
                    acc[5][i][j] = fmaf(hv[i], bv[5][j], acc[5][i][j]);
                }
        }
        __syncthreads();
    }

    #pragma unroll
    for (int j = 0; j < 4; ++j) {
        int d = n0 + tx * 4 + j;
        float br = bih[d]           + bhh[d];
        float bz = bih[D_DIM + d]   + bhh[D_DIM + d];
        float bxn = bih[2 * D_DIM + d];
        float bhn = bhh[2 * D_DIM + d];
        #pragma unroll
        for (int i = 0; i < 4; ++i) {
            int row = m0 + ty * 4 + i;
            float r = sigmoidf_(acc[0][i][j] + acc[3][i][j] + br);
            float z = sigmoidf_(acc[1][i][j] + acc[4][i][j] + bz);
            float hn = acc[5][i][j] + bhn;
            float n = tanhf(acc[2][i][j] + bxn + r * hn);
            float h = superatom[(size_t)row * D_DIM + d];
            out[(size_t)row * D_DIM + d] = (1.0f - z) * n + z * h;
        }
    }
}

extern "C" void kernel_launch(void* const* d_in, const int* in_sizes, int n_in,
                              void* d_out, int out_size, void* d_ws, size_t ws_size,
                              hipStream_t stream) {
    const float* superatom = (const float*)d_in[0];
    const float* atom      = (const float*)d_in[1];
    const int*   mol_index = (const int*)d_in[2];
    const float* align_w   = (const float*)d_in[3];
    const float* align_b   = (const float*)d_in[4];
    const float* attend_w  = (const float*)d_in[5];
    const float* attend_b  = (const float*)d_in[6];
    const float* bn_gamma  = (const float*)d_in[7];
    const float* bn_beta   = (const float*)d_in[8];
    const float* bn_mean   = (const float*)d_in[9];
    const float* bn_var    = (const float*)d_in[10];
    const float* gru_wih   = (const float*)d_in[11];
    const float* gru_whh   = (const float*)d_in[12];
    const float* gru_bih   = (const float*)d_in[13];
    const float* gru_bhh   = (const float*)d_in[14];

    const int M = in_sizes[0] / D_DIM;
    const int N = in_sizes[2];

    float* out     = (float*)d_out;
    float* att_out = out + (size_t)M * D_DIM;   // attention weights [N]

    float* ws      = (float*)d_ws;
    float* ctxwn   = ws;                              // [M, D]
    float* wsum    = ctxwn + (size_t)M * D_DIM;       // [M]
    float* context = wsum + M;                        // [M, D]

    k1_segment<<<M, 256, 0, stream>>>(superatom, atom, mol_index, align_w, align_b,
                                      ctxwn, wsum, att_out, N);
    k2_context<<<dim3(M / 64, D_DIM / 64), 256, 0, stream>>>(ctxwn, attend_w, attend_b,
                                                             bn_gamma, bn_beta, bn_mean, bn_var,
                                                             wsum, context);
    k3_gru<<<dim3(M / 64, D_DIM / 64), 256, 0, stream>>>(context, superatom,
                                                         gru_wih, gru_whh, gru_bih, gru_bhh,
                                                         out);
}

// Round 2
// 854.435 us; speedup vs baseline: 1.2602x; 1.2602x over previous
//
#include <hip/hip_runtime.h>
#include <hip/hip_bf16.h>

#define D_DIM 256
#define EPS_BN 1e-6f
#define EPS_SM 1e-8f

typedef __bf16 bf16x8 __attribute__((ext_vector_type(8)));
typedef __bf16 bf16x4 __attribute__((ext_vector_type(4)));
typedef float  f32x4  __attribute__((ext_vector_type(4)));

__device__ __forceinline__ float wave_reduce_sum(float v) {
    #pragma unroll
    for (int off = 1; off < 64; off <<= 1) v += __shfl_xor(v, off);
    return v;
}

__device__ __forceinline__ float sigmoidf_(float x) {
    return 1.0f / (1.0f + __expf(-x));
}

// ---------------------------------------------------------------------------
// K0: f32 -> bf16 conversions (weights + superatom), one kernel.
// ---------------------------------------------------------------------------
__device__ __forceinline__ void cvt_region(const float* __restrict__ s,
                                           __bf16* __restrict__ d,
                                           int n4, int idx, int stride) {
    const float4* s4 = (const float4*)s;
    bf16x4* d4 = (bf16x4*)d;
    for (int i = idx; i < n4; i += stride) {
        float4 v = s4[i];
        bf16x4 o;
        o[0] = (__bf16)v.x; o[1] = (__bf16)v.y; o[2] = (__bf16)v.z; o[3] = (__bf16)v.w;
        d4[i] = o;
    }
}

__global__ __launch_bounds__(256) void k0_convert(
    const float* __restrict__ superatom, __bf16* __restrict__ sup_bf, int n_sup,
    const float* __restrict__ attend_w,  __bf16* __restrict__ aw_bf,  int n_aw,
    const float* __restrict__ wih,       __bf16* __restrict__ wih_bf, int n_wih,
    const float* __restrict__ whh,       __bf16* __restrict__ whh_bf, int n_whh)
{
    int idx = blockIdx.x * blockDim.x + threadIdx.x;
    int stride = gridDim.x * blockDim.x;
    cvt_region(superatom, sup_bf, n_sup / 4, idx, stride);
    cvt_region(attend_w,  aw_bf,  n_aw / 4,  idx, stride);
    cvt_region(wih,       wih_bf, n_wih / 4, idx, stride);
    cvt_region(whh,       whh_bf, n_whh / 4, idx, stride);
}

// ---------------------------------------------------------------------------
// K1: one block (4 waves) per molecule; contiguous segment via binary search.
// Single pass over atom rows with online softmax (running max/sum/weighted
// atom accumulator per wave, merged across waves at the end).
// att_out holds raw scores during the kernel, final weights at the end.
// ctxwn written as bf16 for the MFMA consumer; wsum in f32.
// ---------------------------------------------------------------------------
__global__ __launch_bounds__(256) void k1_segment(
    const float* __restrict__ superatom,
    const float* __restrict__ atom,
    const int*   __restrict__ mol_index,
    const float* __restrict__ align_w,
    const float* __restrict__ align_b,
    __bf16* __restrict__ ctxwn_bf, // [M, D]
    float* __restrict__ wsum,      // [M]
    float* __restrict__ att_out,   // [N]
    int N)
{
    const int m    = blockIdx.x;
    const int tid  = threadIdx.x;
    const int wid  = tid >> 6;
    const int lane = tid & 63;

    // binary search segment [segs, sege)
    int lo = 0, hi = N;
    while (lo < hi) { int mid = (lo + hi) >> 1; if (mol_index[mid] < m) lo = mid + 1; else hi = mid; }
    const int segs = lo;
    hi = N;
    while (lo < hi) { int mid = (lo + hi) >> 1; if (mol_index[mid] < m + 1) lo = mid + 1; else hi = mid; }
    const int sege = lo;

    // c_m = dot(align_w[0:D], superatom[m]) + b
    const float4* sup4 = (const float4*)(superatom + (size_t)m * D_DIM);
    const float4* w14  = (const float4*)align_w;
    const float4* w24  = (const float4*)(align_w + D_DIM);
    float4 sw = sup4[lane];
    float4 w1 = w14[lane];
    float part = sw.x * w1.x + sw.y * w1.y + sw.z * w1.z + sw.w * w1.w;
    part = wave_reduce_sum(part);
    const float cm = part + align_b[0];
    const float4 wa = w24[lane];

    __shared__ float smax[4];
    __shared__ float ssum[4];
    __shared__ float sacc[4 * D_DIM];

    // ---- single pass: score + online softmax + weighted atom sum ----
    float m_run = -3.4e38f;
    float S = 0.0f;
    float4 acc = make_float4(0.f, 0.f, 0.f, 0.f);
    for (int i = segs + wid; i < sege; i += 4) {
        float4 a = ((const float4*)(atom + (size_t)i * D_DIM))[lane];
        float p = a.x * wa.x + a.y * wa.y + a.z * wa.z + a.w * wa.w;
        p = wave_reduce_sum(p);
        float sc = cm + p;
        sc = sc > 0.0f ? sc : 0.01f * sc;      // leaky_relu(0.01)
        if (lane == 0) att_out[i] = sc;        // stash raw score
        if (sc <= m_run) {                      // wave-uniform branch
            float e = __expf(sc - m_run);
            S += e;
            acc.x = fmaf(e, a.x, acc.x); acc.y = fmaf(e, a.y, acc.y);
            acc.z = fmaf(e, a.z, acc.z); acc.w = fmaf(e, a.w, acc.w);
        } else {
            float corr = __expf(m_run - sc);    // first iter: exp(-huge) = 0
            S = fmaf(S, corr, 1.0f);
            acc.x = fmaf(acc.x, corr, a.x); acc.y = fmaf(acc.y, corr, a.y);
            acc.z = fmaf(acc.z, corr, a.z); acc.w = fmaf(acc.w, corr, a.w);
            m_run = sc;
        }
    }
    if (lane == 0) smax[wid] = m_run;
    __syncthreads();
    const float bmax = fmaxf(fmaxf(smax[0], smax[1]), fmaxf(smax[2], smax[3]));
    // rescale wave-local state to the block max
    {
        float corr = __expf(m_run - bmax);      // 0 if this wave had no atoms
        S *= corr;
        acc.x *= corr; acc.y *= corr; acc.z *= corr; acc.w *= corr;
    }
    ((float4*)sacc)[wid * 64 + lane] = acc;
    if (lane == 0) ssum[wid] = S;
    __syncthreads();

    const float Stot = ssum[0] + ssum[1] + ssum[2] + ssum[3];
    const float inv  = 1.0f / (Stot + EPS_SM);
    float v = sacc[tid] + sacc[D_DIM + tid] + sacc[2 * D_DIM + tid] + sacc[3 * D_DIM + tid];
    ctxwn_bf[(size_t)m * D_DIM + tid] = (__bf16)(v * inv);
    if (tid == 0) wsum[m] = Stot * inv;

    // ---- final weights from stashed scores ----
    for (int i = segs + tid; i < sege; i += 256) {
        att_out[i] = __expf(att_out[i] - bmax) * inv;
    }
}

// ---------------------------------------------------------------------------
// K2 (MFMA): context = elu( (ctxwn @ attend_w^T) * scale + wsum ⊗ cbias )
// Block = 4 waves, tile 64m x 64n; wave w handles rows [m0+16w, +16).
// Frags loaded straight from global (no LDS):
//   A frag: lane holds ctxwn[m0+16w+(lane&15)][k0 + (lane>>4)*8 + j]
//   B frag: lane holds attend_w[n0+16t+(lane&15)][k0 + (lane>>4)*8 + j]
// C/D: row = (lane>>4)*4 + reg, col = lane&15.
// ---------------------------------------------------------------------------
__global__ __launch_bounds__(256) void k2_context(
    const __bf16* __restrict__ A,    // ctxwn_bf [M,256]
    const __bf16* __restrict__ W,    // attend_w bf16 [256,256]
    const float* __restrict__ attend_b,
    const float* __restrict__ gamma_, const float* __restrict__ beta_,
    const float* __restrict__ mean_,  const float* __restrict__ var_,
    const float* __restrict__ wsum,
    __bf16* __restrict__ context_bf) // [M,256]
{
    const int tid  = threadIdx.x;
    const int wid  = tid >> 6;
    const int lane = tid & 63;
    const int quad = lane >> 4;
    const int r16  = lane & 15;
    const int m0   = blockIdx.x * 64;
    const int n0   = blockIdx.y * 64;

    const int arow = m0 + wid * 16 + r16;
    f32x4 acc[4] = {};

    #pragma unroll
    for (int ks = 0; ks < 8; ++ks) {
        const int ko = ks * 32 + quad * 8;
        bf16x8 af = *(const bf16x8*)&A[(size_t)arow * D_DIM + ko];
        #pragma unroll
        for (int t = 0; t < 4; ++t) {
            bf16x8 bf = *(const bf16x8*)&W[(size_t)(n0 + t * 16 + r16) * D_DIM + ko];
            acc[t] = __builtin_amdgcn_mfma_f32_16x16x32_bf16(af, bf, acc[t], 0, 0, 0);
        }
    }

    #pragma unroll
    for (int t = 0; t < 4; ++t) {
        const int col = n0 + t * 16 + r16;
        const float sc = gamma_[col] * rsqrtf(var_[col] + EPS_BN);
        const float cb = (attend_b[col] - mean_[col]) * sc + beta_[col];
        #pragma unroll
        for (int r = 0; r < 4; ++r) {
            const int row = m0 + wid * 16 + quad * 4 + r;
            float pre = acc[t][r] * sc + wsum[row] * cb;
            float e = pre > 0.0f ? pre : (__expf(pre) - 1.0f);
            context_bf[(size_t)row * D_DIM + col] = (__bf16)e;
        }
    }
}

// ---------------------------------------------------------------------------
// K3 (MFMA): fused GRU. Per block: 64m x 64d tile of the final update,
// 6 sub-GEMMs (context x wih_{r,z,n}, superatom x whh_{r,z,n}) accumulated
// in registers, gates in the epilogue (h read exactly from f32 superatom).
// ---------------------------------------------------------------------------
__global__ __launch_bounds__(256) void k3_gru(
    const __bf16* __restrict__ ctx_bf,  // [M,256]
    const __bf16* __restrict__ sup_bf,  // [M,256]
    const float*  __restrict__ superatom, // f32, exact h for the z-blend
    const __bf16* __restrict__ wih_bf,  // [768,256]
    const __bf16* __restrict__ whh_bf,  // [768,256]
    const float* __restrict__ bih,
    const float* __restrict__ bhh,
    float* __restrict__ out)            // [M,256]
{
    const int tid  = threadIdx.x;
    const int wid  = tid >> 6;
    const int lane = tid & 63;
    const int quad = lane >> 4;
    const int r16  = lane & 15;
    const int m0   = blockIdx.x * 64;
    const int n0   = blockIdx.y * 64;

    const int arow = m0 + wid * 16 + r16;
    f32x4 acc[6][4] = {};

    #pragma unroll
    for (int ks = 0; ks < 8; ++ks) {
        const int ko = ks * 32 + quad * 8;
        bf16x8 ca = *(const bf16x8*)&ctx_bf[(size_t)arow * D_DIM + ko];
        bf16x8 ha = *(const bf16x8*)&sup_bf[(size_t)arow * D_DIM + ko];
        #pragma unroll
        for (int t = 0; t < 4; ++t) {
            const int brow = n0 + t * 16 + r16;
            bf16x8 b0 = *(const bf16x8*)&wih_bf[(size_t)(0 * D_DIM + brow) * D_DIM + ko];
            bf16x8 b1 = *(const bf16x8*)&wih_bf[(size_t)(1 * D_DIM + brow) * D_DIM + ko];
            bf16x8 b2 = *(const bf16x8*)&wih_bf[(size_t)(2 * D_DIM + brow) * D_DIM + ko];
            bf16x8 b3 = *(const bf16x8*)&whh_bf[(size_t)(0 * D_DIM + brow) * D_DIM + ko];
            bf16x8 b4 = *(const bf16x8*)&whh_bf[(size_t)(1 * D_DIM + brow) * D_DIM + ko];
            bf16x8 b5 = *(const bf16x8*)&whh_bf[(size_t)(2 * D_DIM + brow) * D_DIM + ko];
            acc[0][t] = __builtin_amdgcn_mfma_f32_16x16x32_bf16(ca, b0, acc[0][t], 0, 0, 0);
            acc[1][t] = __builtin_amdgcn_mfma_f32_16x16x32_bf16(ca, b1, acc[1][t], 0, 0, 0);
            acc[2][t] = __builtin_amdgcn_mfma_f32_16x16x32_bf16(ca, b2, acc[2][t], 0, 0, 0);
            acc[3][t] = __builtin_amdgcn_mfma_f32_16x16x32_bf16(ha, b3, acc[3][t], 0, 0, 0);
            acc[4][t] = __builtin_amdgcn_mfma_f32_16x16x32_bf16(ha, b4, acc[4][t], 0, 0, 0);
            acc[5][t] = __builtin_amdgcn_mfma_f32_16x16x32_bf16(ha, b5, acc[5][t], 0, 0, 0);
        }
    }

    #pragma unroll
    for (int t = 0; t < 4; ++t) {
        const int col = n0 + t * 16 + r16;
        const float br  = bih[col]             + bhh[col];
        const float bz  = bih[D_DIM + col]     + bhh[D_DIM + col];
        const float bxn = bih[2 * D_DIM + col];
        const float bhn = bhh[2 * D_DIM + col];
        #pragma unroll
        for (int r = 0; r < 4; ++r) {
            const int row = m0 + wid * 16 + quad * 4 + r;
            float rg = sigmoidf_(acc[0][t][r] + acc[3][t][r] + br);
            float z  = sigmoidf_(acc[1][t][r] + acc[4][t][r] + bz);
            float n  = tanhf(acc[2][t][r] + bxn + rg * (acc[5][t][r] + bhn));
            float h  = superatom[(size_t)row * D_DIM + col];
            out[(size_t)row * D_DIM + col] = (1.0f - z) * n + z * h;
        }
    }
}

extern "C" void kernel_launch(void* const* d_in, const int* in_sizes, int n_in,
                              void* d_out, int out_size, void* d_ws, size_t ws_size,
                              hipStream_t stream) {
    const float* superatom = (const float*)d_in[0];
    const float* atom      = (const float*)d_in[1];
    const int*   mol_index = (const int*)d_in[2];
    const float* align_w   = (const float*)d_in[3];
    const float* align_b   = (const float*)d_in[4];
    const float* attend_w  = (const float*)d_in[5];
    const float* attend_b  = (const float*)d_in[6];
    const float* bn_gamma  = (const float*)d_in[7];
    const float* bn_beta   = (const float*)d_in[8];
    const float* bn_mean   = (const float*)d_in[9];
    const float* bn_var    = (const float*)d_in[10];
    const float* gru_wih   = (const float*)d_in[11];
    const float* gru_whh   = (const float*)d_in[12];
    const float* gru_bih   = (const float*)d_in[13];
    const float* gru_bhh   = (const float*)d_in[14];

    const int M = in_sizes[0] / D_DIM;
    const int N = in_sizes[2];

    float* out     = (float*)d_out;
    float* att_out = out + (size_t)M * D_DIM;   // attention weights [N]

    // workspace layout (16B-aligned chunks)
    char* ws = (char*)d_ws;
    __bf16* ctxwn_bf   = (__bf16*)ws;                     ws += (size_t)M * D_DIM * 2;
    __bf16* context_bf = (__bf16*)ws;                     ws += (size_t)M * D_DIM * 2;
    __bf16* sup_bf     = (__bf16*)ws;                     ws += (size_t)M * D_DIM * 2;
    __bf16* aw_bf      = (__bf16*)ws;                     ws += (size_t)D_DIM * D_DIM * 2;
    __bf16* wih_bf     = (__bf16*)ws;                     ws += (size_t)3 * D_DIM * D_DIM * 2;
    __bf16* whh_bf     = (__bf16*)ws;                     ws += (size_t)3 * D_DIM * D_DIM * 2;
    float*  wsum       = (float*)ws;                      ws += (size_t)M * 4;

    k0_convert<<<512, 256, 0, stream>>>(superatom, sup_bf, M * D_DIM,
                                        attend_w, aw_bf, D_DIM * D_DIM,
                                        gru_wih, wih_bf, 3 * D_DIM * D_DIM,
                                        gru_whh, whh_bf, 3 * D_DIM * D_DIM);
    k1_segment<<<M, 256, 0, stream>>>(superatom, atom, mol_index, align_w, align_b,
                                      ctxwn_bf, wsum, att_out, N);
    k2_context<<<dim3(M / 64, D_DIM / 64), 256, 0, stream>>>(ctxwn_bf, aw_bf, attend_b,
                                                             bn_gamma, bn_beta, bn_mean, bn_var,
                                                             wsum, context_bf);
    k3_gru<<<dim3(M / 64, D_DIM / 64), 256, 0, stream>>>(context_bf, sup_bf, superatom,
                                                         wih_bf, whh_bf, gru_bih, gru_bhh,
                                                         out);
}